// Round 2
// baseline (1694.783 us; speedup 1.0000x reference)
//
#include <hip/hip_runtime.h>

// ---------------- problem constants ----------------
#define NB 64
#define NT 256
#define BT 16384          // NB*NT
#define NG 66
#define START_ 64
#define STOP_ 65
#define INV_TEMP 0.08838834764831845f  // 1/sqrt(128)

typedef _Float16 half2_t __attribute__((ext_vector_type(2)));
typedef _Float16 h8 __attribute__((ext_vector_type(8)));
typedef float f4x __attribute__((ext_vector_type(4)));
union H2U { unsigned u; half2_t h; };

// ---------------- workspace layout (float offsets) ----------------
// preF fp32 [BT][1024] @ 0          (16,777,216)
//   (attention temporaries alias preF region — all dead before pre-GEMMs:)
//   ce_pad_h fp16 [64][258][128] @ 0          (1,056,768 f)
//   q_h      fp16 [BT][512]      @ 1,056,768  (4,194,304 f)
//   scores   fp32 [64][256][256] @ 5,251,072  (4,194,304 f)
//   P_h      fp16 [64][256][256] @ 9,445,376  (2,097,152 f)
//   kvT_h    fp16 [64][512][256] @ 11,542,528 (4,194,304 f)
// preB fp32 [BT][1024] @ 16,777,216 (16,777,216)
//   kv_h fp16 [BT][512] @ 16,777,216 (4,194,304 f) — dead before preB written
// x1_h fp16 [BT][512] @ 33,554,432 (4,194,304 f)   attn out; later layer-2 out
// y_h  fp16 [BT][512] @ 37,748,736 (4,194,304 f)   layer-1 out
// wt   fp16 [4][64kq][1024] @ 41,943,040 (524,288 f)
// wih_h fp16 [4][1024][512] @ 42,467,328 (1,048,576 f)
// projw_h fp16 [66][512]    @ 43,515,904 (16,896 f)
// w2_h fp16 [384][384]      @ 43,532,800 (73,728 f)
// emit fp32 [BT][66]        @ 43,606,528 (1,081,344 f)
#define OFF_PREF   0L
#define OFF_CEPADH 0L
#define OFF_QH     1056768L
#define OFF_SC     5251072L
#define OFF_PH     9445376L
#define OFF_KVT    11542528L
#define OFF_PREB   16777216L
#define OFF_KVH    16777216L
#define OFF_X1H    33554432L
#define OFF_YH     37748736L
#define OFF_WT     41943040L
#define OFF_WIH    42467328L
#define OFF_PROJW  43515904L
#define OFF_W2H    43532800L
#define OFF_EMIT   43606528L

__device__ __forceinline__ float fsig(float x) {
    return 1.f / (1.f + __expf(-x));
}
__device__ __forceinline__ float ftanh(float x) {
    float xc = fminf(fmaxf(x, -15.f), 15.f);
    float e = __expf(2.f * xc);
    return (e - 1.f) / (e + 1.f);
}
__device__ __forceinline__ uint2 f4h(float4 v) {
    H2U a, b;
    a.h[0] = (_Float16)v.x; a.h[1] = (_Float16)v.y;
    b.h[0] = (_Float16)v.z; b.h[1] = (_Float16)v.w;
    return make_uint2(a.u, b.u);
}

// ---------------- embedding / gather (fp16 outputs) ----------------
__global__ __launch_bounds__(128) void embed_k(
    const int* __restrict__ word, const int* __restrict__ intents,
    const int* __restrict__ chars, const int* __restrict__ lexi,
    const float* __restrict__ word_emb, const float* __restrict__ lexi_emb,
    const float* __restrict__ intent_emb, const float* __restrict__ char_emb,
    _Float16* __restrict__ kvh, _Float16* __restrict__ qh, _Float16* __restrict__ cepad)
{
    int bt = blockIdx.x;
    int b = bt >> 8, t = bt & 255;
    int tid = threadIdx.x;
    const float4* wrow = (const float4*)(word_emb + (long)word[bt] * 256);
    const float4* lrow = (const float4*)(lexi_emb + (long)lexi[bt] * 128);
    const float4* irow = (const float4*)(intent_emb + (long)intents[b] * 128);
    const float4* crow = (const float4*)(char_emb + (long)chars[bt] * 128);
    uint2* kvrow = (uint2*)(kvh + (long)bt * 512);
    uint2* qrow  = (uint2*)(qh + (long)bt * 512);
    uint2* cerow = (uint2*)(cepad + ((long)b * 258 + t + 1) * 128);
    if (tid < 64)       kvrow[tid] = f4h(wrow[tid]);
    else if (tid < 96)  kvrow[tid] = f4h(lrow[tid - 64]);
    else { uint2 v = f4h(irow[tid - 96]); kvrow[tid] = v; qrow[tid] = v; }
    if (tid < 32) cerow[tid] = f4h(crow[tid]);
    if (t == 0) {
        uint2 z = make_uint2(0u, 0u);
        if (tid < 32)      ((uint2*)(cepad + (long)b * 258 * 128))[tid] = z;
        else if (tid < 64) ((uint2*)(cepad + ((long)b * 258 + 257) * 128))[tid - 32] = z;
    }
}

// repack conv_w (O,C,K) -> w2_h fp16 [o][k*128+c]; zero loss slot
__global__ __launch_bounds__(256) void prep_k(const float* __restrict__ conv_w,
                                              _Float16* __restrict__ w2,
                                              float* __restrict__ out0)
{
    int idx = blockIdx.x * 256 + threadIdx.x;
    if (idx == 0) out0[0] = 0.f;
    if (idx < 384 * 384) {
        int o = idx / 384, r = idx % 384;
        int k = r >> 7, c = r & 127;
        w2[o * 384 + r] = (_Float16)conv_w[o * 384 + c * 3 + k];
    }
}

// fp32 -> fp16 elementwise (n multiple of 1024; 4 elems/thread)
__global__ __launch_bounds__(256) void cvt_k(const float* __restrict__ src,
                                             uint2* __restrict__ dst)
{
    long i = ((long)blockIdx.x * 256 + threadIdx.x);
    dst[i] = f4h(((const float4*)src)[i]);
}

// transpose+pack w_hh fp32 [4 ld][1024 row][256 k]
//   -> wt fp16 uint2 [4 ld][64 kq][1024 row]
__global__ __launch_bounds__(256) void wt_k(const float* __restrict__ whh,
                                            uint2* __restrict__ wt)
{
    int bid = blockIdx.x;
    int ld = bid >> 6;
    int rt = (bid >> 2) & 15;
    int kt = bid & 3;
    const float* src = whh + ((long)ld * 1024 + rt * 64) * 256 + kt * 64;
    __shared__ float tile[64][65];
    int c = threadIdx.x & 63, r0 = threadIdx.x >> 6;  // r0 in 0..3
#pragma unroll
    for (int i = 0; i < 16; i++)
        tile[r0 + i * 4][c] = src[(long)(r0 + i * 4) * 256 + c];
    __syncthreads();
    uint2* dst = wt + (long)ld * 65536;
#pragma unroll
    for (int i = 0; i < 4; i++) {
        int kql = r0 + i * 4;          // 0..15
        H2U ua, ub;
        ua.h[0] = (_Float16)tile[c][4 * kql + 0];
        ua.h[1] = (_Float16)tile[c][4 * kql + 1];
        ub.h[0] = (_Float16)tile[c][4 * kql + 2];
        ub.h[1] = (_Float16)tile[c][4 * kql + 3];
        dst[(long)(kt * 16 + kql) * 1024 + rt * 64 + c] = make_uint2(ua.u, ub.u);
    }
}

// fp16 transpose kv [b][256 t][512 d] -> kvT [b][512 d][256 t]
__global__ __launch_bounds__(256) void tr_k(const _Float16* __restrict__ kv,
                                            _Float16* __restrict__ kvT)
{
    int bid = blockIdx.x;                 // 64 b * 8 dt * 4 tt = 2048
    int b = bid >> 5, rem = bid & 31;
    int dt = rem >> 2, tt = rem & 3;
    __shared__ _Float16 tile[64][66];
    int c = threadIdx.x & 63, r0 = threadIdx.x >> 6;
    const _Float16* src = kv + ((long)b * 256 + tt * 64) * 512 + dt * 64;
#pragma unroll
    for (int i = 0; i < 16; i++)
        tile[r0 + i * 4][c] = src[(long)(r0 + i * 4) * 512 + c];
    __syncthreads();
    _Float16* dst = kvT + ((long)b * 512 + dt * 64) * 256 + tt * 64;
#pragma unroll
    for (int i = 0; i < 16; i++)
        dst[(long)(r0 + i * 4) * 256 + c] = tile[c][r0 + i * 4];
}

// ---------------- generalized fp16 MFMA GEMM ----------------
// C = alpha * A(MxK) @ B(NxK)^T + bias0 + bias1.  128x128 tile, 2x2 waves, BK=32.
// amode=1: A rows gathered from ce_pad layout (row m -> m*128 + (m>>8)*256, 384 contiguous halves).
// c_half: store fp16 else fp32. N-guard in staging (clamp) and epilogue (mask).
__global__ __launch_bounds__(256) void hgemm_k(
    const _Float16* __restrict__ A, int K, long sA, int amode,
    const _Float16* __restrict__ Bm, long sB, int N,
    void* __restrict__ Cv, long sC, int ldc, int c_half,
    const float* __restrict__ bias0, const float* __restrict__ bias1, float alpha)
{
    A  += (long)blockIdx.z * sA;
    Bm += (long)blockIdx.z * sB;
    const long cbase = (long)blockIdx.z * sC;
    const int m0 = blockIdx.x * 128, n0 = blockIdx.y * 128;
    const int tid = threadIdx.x;
    const int lane = tid & 63, wave = tid >> 6;
    const int wm = (wave & 1) * 64, wn = (wave >> 1) * 64;
    __shared__ _Float16 As[128][40];
    __shared__ _Float16 Bs[128][40];
    f4x acc[4][4];
#pragma unroll
    for (int i = 0; i < 4; i++)
#pragma unroll
        for (int j = 0; j < 4; j++) acc[i][j] = (f4x){0.f, 0.f, 0.f, 0.f};

    const int sr = tid & 127;
    const int sk = (tid >> 7) * 16;
    const int fm = lane & 15, fq = lane >> 4;
    const int mr = m0 + sr;
    const long aoff = amode ? ((long)mr * 128 + (long)(mr >> 8) * 256) : ((long)mr * K);
    int nr = n0 + sr; if (nr >= N) nr = N - 1;

    for (int k0 = 0; k0 < K; k0 += 32) {
        const uint4* ga = (const uint4*)(A + aoff + k0 + sk);
        const uint4* gb = (const uint4*)(Bm + (long)nr * K + k0 + sk);
        uint4 va0 = ga[0], va1 = ga[1];
        uint4 vb0 = gb[0], vb1 = gb[1];
        *(uint4*)&As[sr][sk] = va0; *(uint4*)&As[sr][sk + 8] = va1;
        *(uint4*)&Bs[sr][sk] = vb0; *(uint4*)&Bs[sr][sk + 8] = vb1;
        __syncthreads();
        h8 af[4], bf[4];
#pragma unroll
        for (int i = 0; i < 4; i++) af[i] = *(const h8*)&As[wm + i * 16 + fm][fq * 8];
#pragma unroll
        for (int i = 0; i < 4; i++) bf[i] = *(const h8*)&Bs[wn + i * 16 + fm][fq * 8];
#pragma unroll
        for (int i = 0; i < 4; i++)
#pragma unroll
            for (int j = 0; j < 4; j++)
                acc[i][j] = __builtin_amdgcn_mfma_f32_16x16x32_f16(af[i], bf[j], acc[i][j], 0, 0, 0);
        __syncthreads();
    }
    const int col = lane & 15, rowb = (lane >> 4) * 4;
#pragma unroll
    for (int i = 0; i < 4; i++) {
#pragma unroll
        for (int j = 0; j < 4; j++) {
            int n = n0 + wn + j * 16 + col;
            if (n < N) {
                float bsum = (bias0 ? bias0[n] : 0.f) + (bias1 ? bias1[n] : 0.f);
#pragma unroll
                for (int r = 0; r < 4; r++) {
                    int m = m0 + wm + i * 16 + rowb + r;
                    float v = acc[i][j][r] * alpha + bsum;
                    if (c_half) ((_Float16*)Cv)[cbase + (long)m * ldc + n] = (_Float16)v;
                    else        ((float*)Cv)[cbase + (long)m * ldc + n] = v;
                }
            }
        }
    }
}

// ---------------- row softmax over 256 cols: fp32 in, fp16 out ----------------
__global__ __launch_bounds__(256) void softmax_k(const float* __restrict__ scores,
                                                 _Float16* __restrict__ P)
{
    int row = blockIdx.x * 4 + (threadIdx.x >> 6);
    int lane = threadIdx.x & 63;
    const float4* p = (const float4*)(scores + (long)row * 256);
    float4 v = p[lane];
    float m = fmaxf(fmaxf(v.x, v.y), fmaxf(v.z, v.w));
#pragma unroll
    for (int off = 32; off; off >>= 1) m = fmaxf(m, __shfl_xor(m, off));
    v.x = __expf(v.x - m); v.y = __expf(v.y - m);
    v.z = __expf(v.z - m); v.w = __expf(v.w - m);
    float s = v.x + v.y + v.z + v.w;
#pragma unroll
    for (int off = 32; off; off >>= 1) s += __shfl_xor(s, off);
    float inv = 1.f / s;
    v.x *= inv; v.y *= inv; v.z *= inv; v.w *= inv;
    ((uint2*)(P + (long)row * 256))[lane] = f4h(v);
}

// ---------------- BiLSTM recurrence v7 ----------------
// v7 changes vs v6:
//  * __launch_bounds__(512, 1): LDS (132.6 KB) already limits to 1 block/CU, so the
//    old (512,2) declaration only capped regs at 128/thread and forced wreg[40]
//    (160 VGPRs) through AGPR/scratch every timestep. 256-reg budget makes the
//    register weight cache fully resident.
//  * 4 accumulators (a0/b0 for gate r0, a1/b1 for gate r0+1): with only 2 waves/SIMD
//    the ILP-2 fdot2 dependency chains couldn't saturate issue.
__global__ __launch_bounds__(512, 1) void lstm_k(
    const float* __restrict__ preF, const float* __restrict__ preB,
    const uint4* __restrict__ wtL,   // layer base: [2 dir][64 kq][512 rp] uint4
    _Float16* __restrict__ out)      // [BT][512] fp16, cols dir*256+j
{
    const int dir = blockIdx.x & 1;
    const int b   = blockIdx.x >> 1;
    const int tid = threadIdx.x;
    const int r0  = tid * 2;
    __shared__ uint4 wlds[16][512];     // kq 40..55 (128 KB)
    __shared__ __align__(16) _Float16 hq16[256];
    __shared__ float gl[1024];
    const float* pre = (dir ? preB : preF) + (long)b * 256 * 1024;
    const uint4* W = wtL + (long)dir * 32768;

    uint4 wreg[40];
#pragma unroll
    for (int i = 0; i < 40; i++) wreg[i] = W[i * 512 + tid];
#pragma unroll
    for (int i = 0; i < 16; i++) wlds[i][tid] = W[(40 + i) * 512 + tid];
    float cst = 0.f;
    __syncthreads();

#define DOT(WV, HV) do {                                                         \
    H2U wx, wy, wz, ww, hx, hy;                                                  \
    wx.u = (WV).x; wy.u = (WV).y; wz.u = (WV).z; ww.u = (WV).w;                  \
    hx.u = (HV).x; hy.u = (HV).y;                                                \
    a0 = __builtin_amdgcn_fdot2(wx.h, hx.h, a0, false);                          \
    b0 = __builtin_amdgcn_fdot2(wy.h, hy.h, b0, false);                          \
    a1 = __builtin_amdgcn_fdot2(wz.h, hx.h, a1, false);                          \
    b1 = __builtin_amdgcn_fdot2(ww.h, hy.h, b1, false);                          \
} while (0)

    for (int t = 0; t < 256; t++) {
        const int tpre = dir ? (255 - t) : t;
        float2 p = *(const float2*)(pre + (long)tpre * 1024 + r0);
        float a0 = 0.f, a1 = 0.f, b0 = 0.f, b1 = 0.f;
        if (t > 0) {
            uint4 s0[8];
            // issue streamed chunk (kq 56..63) — latency covered by cached compute
#pragma unroll
            for (int i = 0; i < 8; i++) s0[i] = W[(56 + i) * 512 + tid];
            // register-cached kq 0..39 (paired h reads: one b128 per 2 kq)
#pragma unroll
            for (int i = 0; i < 20; i++) {
                uint4 h4 = *(const uint4*)&hq16[i * 8];
                uint2 ha = make_uint2(h4.x, h4.y), hb = make_uint2(h4.z, h4.w);
                DOT(wreg[2 * i], ha);
                DOT(wreg[2 * i + 1], hb);
            }
            // LDS-cached kq 40..55
#pragma unroll
            for (int i = 0; i < 8; i++) {
                uint4 h4 = *(const uint4*)&hq16[(40 + 2 * i) * 4];
                uint2 ha = make_uint2(h4.x, h4.y), hb = make_uint2(h4.z, h4.w);
                uint4 w0 = wlds[2 * i][tid];
                uint4 w1 = wlds[2 * i + 1][tid];
                DOT(w0, ha);
                DOT(w1, hb);
            }
            // consume streamed chunk
#pragma unroll
            for (int i = 0; i < 4; i++) {
                uint4 h4 = *(const uint4*)&hq16[(56 + 2 * i) * 4];
                uint2 ha = make_uint2(h4.x, h4.y), hb = make_uint2(h4.z, h4.w);
                DOT(s0[2 * i], ha);
                DOT(s0[2 * i + 1], hb);
            }
        }
        *(float2*)&gl[r0] = make_float2(a0 + b0 + p.x, a1 + b1 + p.y);
        __syncthreads();
        // ---- update phase: tid<256, thread owns h-dim j ----
        if (tid < 256) {
            const int j = tid;
            float gi = gl[j], gf = gl[256 + j], gg = gl[512 + j], go = gl[768 + j];
            float si = fsig(gi), sf = fsig(gf), so = fsig(go);
            cst = sf * cst + si * ftanh(gg);
            float h = so * ftanh(cst);
            _Float16 hh = (_Float16)h;
            hq16[j] = hh;
            out[((long)b * 256 + tpre) * 512 + dir * 256 + j] = hh;
        }
        __syncthreads();
    }
#undef DOT
}

// ---------------- CRF NLL + Viterbi (register-cached T columns, vectorized) ----------------
__global__ __launch_bounds__(128) void crf_k(
    const float* __restrict__ emit, const float* __restrict__ trans,
    const int* __restrict__ labels, float* __restrict__ outv)
{
    const int b = blockIdx.x & 63;
    const bool vit = blockIdx.x >= 64;
    const int tid = threadIdx.x;
    __shared__ float Tl[NG * NG];
    __shared__ __align__(16) float bufA[68];
    __shared__ __align__(16) float bufB[68];
    __shared__ unsigned char bp[256][NG];
    __shared__ float redv[128];
    for (int i = tid; i < NG * NG; i += 128) Tl[i] = trans[i];
    __syncthreads();
    const float* eb = emit + (long)b * 256 * NG;

    float tcol[68];
    if (tid < NG) {
#pragma unroll
        for (int i = 0; i < NG; i++) tcol[i] = Tl[i * NG + tid];
    }
    tcol[66] = 0.f; tcol[67] = 0.f;
    if (tid < NG) bufA[tid] = Tl[START_ * NG + tid] + eb[tid];
    if (tid == 66 || tid == 67) { bufA[tid] = -1e30f; bufB[tid] = -1e30f; }
    __syncthreads();

    if (!vit) {
        for (int t = 1; t < 256; t++) {
            const float* prev = (t & 1) ? bufA : bufB;
            float* cur  = (t & 1) ? bufB : bufA;
            float e_t = (tid < NG) ? eb[t * NG + tid] : 0.f;
            if (tid < NG) {
                float pv[68];
#pragma unroll
                for (int c = 0; c < 17; c++) {
                    float4 p4 = *(const float4*)&prev[c * 4];
                    pv[c * 4 + 0] = p4.x + tcol[c * 4 + 0];
                    pv[c * 4 + 1] = p4.y + tcol[c * 4 + 1];
                    pv[c * 4 + 2] = p4.z + tcol[c * 4 + 2];
                    pv[c * 4 + 3] = p4.w + tcol[c * 4 + 3];
                }
                float m0 = -1e30f, m1 = -1e30f, m2 = -1e30f, m3 = -1e30f;
#pragma unroll
                for (int c = 0; c < 17; c++) {
                    m0 = fmaxf(m0, pv[c * 4 + 0]);
                    m1 = fmaxf(m1, pv[c * 4 + 1]);
                    m2 = fmaxf(m2, pv[c * 4 + 2]);
                    m3 = fmaxf(m3, pv[c * 4 + 3]);
                }
                float m = fmaxf(fmaxf(m0, m1), fmaxf(m2, m3));
                float s0 = 0.f, s1 = 0.f, s2 = 0.f, s3 = 0.f;
#pragma unroll
                for (int c = 0; c < 17; c++) {
                    s0 += __expf(pv[c * 4 + 0] - m);
                    s1 += __expf(pv[c * 4 + 1] - m);
                    s2 += __expf(pv[c * 4 + 2] - m);
                    s3 += __expf(pv[c * 4 + 3] - m);
                }
                cur[tid] = m + __logf((s0 + s1) + (s2 + s3)) + e_t;
            }
            __syncthreads();
        }
        const int* lab = labels + b * 256;
        float g = 0.f;
        for (int t = tid; t < 256; t += 128) g += eb[t * NG + lab[t]];
        for (int t = tid; t < 255; t += 128) g += Tl[lab[t] * NG + lab[t + 1]];
        redv[tid] = g;
        __syncthreads();
        if (tid == 0) {
            float* fin = bufB;
            float m = -1e30f;
            for (int j = 0; j < NG; j++) m = fmaxf(m, fin[j] + Tl[j * NG + STOP_]);
            float s = 0.f;
            for (int j = 0; j < NG; j++) s += __expf(fin[j] + Tl[j * NG + STOP_] - m);
            float logZ = m + __logf(s);
            float gold = Tl[START_ * NG + lab[0]] + Tl[lab[255] * NG + STOP_];
            for (int i = 0; i < 128; i++) gold += redv[i];
            atomicAdd(outv, logZ - gold);
        }
    } else {
        for (int t = 1; t < 256; t++) {
            const float* prev = (t & 1) ? bufA : bufB;
            float* cur  = (t & 1) ? bufB : bufA;
            float e_t = (tid < NG) ? eb[t * NG + tid] : 0.f;
            if (tid < NG) {
                float m = -1e30f; int arg = 0;
#pragma unroll
                for (int c = 0; c < 17; c++) {
                    float4 p4 = *(const float4*)&prev[c * 4];
                    float v0 = p4.x + tcol[c * 4 + 0];
                    float v1 = p4.y + tcol[c * 4 + 1];
                    float v2 = p4.z + tcol[c * 4 + 2];
                    float v3 = p4.w + tcol[c * 4 + 3];
                    if (v0 > m) { m = v0; arg = c * 4 + 0; }
                    if (v1 > m) { m = v1; arg = c * 4 + 1; }
                    if (v2 > m) { m = v2; arg = c * 4 + 2; }
                    if (v3 > m) { m = v3; arg = c * 4 + 3; }
                }
                bp[t][tid] = (unsigned char)arg;
                cur[tid] = m + e_t;
            }
            __syncthreads();
        }
        if (tid == 0) {
            float* fin = bufB;
            float m = -1e30f; int tag = 0;
            for (int j = 0; j < NG; j++) {
                float v = fin[j] + Tl[j * NG + STOP_];
                if (v > m) { m = v; tag = j; }
            }
            float* od = outv + 1 + (long)b * 256;
            od[255] = (float)tag;
            for (int t = 255; t >= 1; t--) { tag = bp[t][tag]; od[t - 1] = (float)tag; }
        }
    }
}

// ---------------- host ----------------
extern "C" void kernel_launch(void* const* d_in, const int* in_sizes, int n_in,
                              void* d_out, int out_size, void* d_ws, size_t ws_size,
                              hipStream_t stream)
{
    const int*   batch_word    = (const int*)d_in[0];
    const int*   batch_intents = (const int*)d_in[1];
    const int*   batch_char    = (const int*)d_in[3];
    const int*   batch_lexi    = (const int*)d_in[6];
    const int*   batch_label   = (const int*)d_in[7];
    const float* char_emb      = (const float*)d_in[8];
    const float* word_emb      = (const float*)d_in[9];
    const float* lexi_emb      = (const float*)d_in[10];
    const float* intent_emb    = (const float*)d_in[11];
    const float* conv_w        = (const float*)d_in[12];
    const float* conv_b        = (const float*)d_in[13];
    const float* w_ih          = (const float*)d_in[14];
    const float* w_hh          = (const float*)d_in[15];
    const float* b_ih          = (const float*)d_in[16];
    const float* b_hh          = (const float*)d_in[17];
    const float* proj_w        = (const float*)d_in[18];
    const float* proj_b        = (const float*)d_in[19];
    const float* trans         = (const float*)d_in[20];
    float* out = (float*)d_out;
    float* ws  = (float*)d_ws;

    float*    preF   = ws + OFF_PREF;
    float*    preB   = ws + OFF_PREB;
    float*    scores = ws + OFF_SC;
    float*    emit   = ws + OFF_EMIT;
    _Float16* cepadh = (_Float16*)(ws + OFF_CEPADH);
    _Float16* qh     = (_Float16*)(ws + OFF_QH);
    _Float16* Ph     = (_Float16*)(ws + OFF_PH);
    _Float16* kvTh   = (_Float16*)(ws + OFF_KVT);
    _Float16* kvh    = (_Float16*)(ws + OFF_KVH);
    _Float16* x1h    = (_Float16*)(ws + OFF_X1H);
    _Float16* yh     = (_Float16*)(ws + OFF_YH);
    uint2*    wt_u2  = (uint2*)(ws + OFF_WT);
    _Float16* wihh   = (_Float16*)(ws + OFF_WIH);
    _Float16* projwh = (_Float16*)(ws + OFF_PROJW);
    _Float16* w2h    = (_Float16*)(ws + OFF_W2H);

    embed_k<<<BT, 128, 0, stream>>>(batch_word, batch_intents, batch_char, batch_lexi,
                                    word_emb, lexi_emb, intent_emb, char_emb,
                                    kvh, qh, cepadh);
    prep_k<<<(384 * 384 + 255) / 256, 256, 0, stream>>>(conv_w, w2h, out);
    wt_k<<<256, 256, 0, stream>>>(w_hh, wt_u2);
    cvt_k<<<2048, 256, 0, stream>>>(w_ih, (uint2*)wihh);
    cvt_k<<<33, 256, 0, stream>>>(proj_w, (uint2*)projwh);
    tr_k<<<2048, 256, 0, stream>>>(kvh, kvTh);

    // char CNN: q_h[:, 0:384] = ce_pad_h @ w2_h^T + conv_b   (amode A-gather)
    hgemm_k<<<dim3(128, 3, 1), 256, 0, stream>>>(
        cepadh, 384, 0L, 1, w2h, 0L, 384,
        qh, 0L, 512, 1, conv_b, nullptr, 1.f);
    // scores = q_h @ kv_h^T * INV_TEMP  (batched, fp32 out)
    hgemm_k<<<dim3(2, 2, NB), 256, 0, stream>>>(
        qh, 512, 131072L, 0, kvh, 131072L, 256,
        scores, 65536L, 256, 0, nullptr, nullptr, INV_TEMP);
    softmax_k<<<4096, 256, 0, stream>>>(scores, Ph);
    // x1 = P_h @ kvT_h^T  (batched, fp16 out)
    hgemm_k<<<dim3(2, 4, NB), 256, 0, stream>>>(
        Ph, 256, 65536L, 0, kvTh, 131072L, 512,
        x1h, 131072L, 512, 1, nullptr, nullptr, 1.f);

    for (int l = 0; l < 2; l++) {
        const _Float16* xin = l ? yh : x1h;
        _Float16* xout = l ? x1h : yh;
        for (int d = 0; d < 2; d++) {
            hgemm_k<<<dim3(128, 8, 1), 256, 0, stream>>>(
                xin, 512, 0L, 0, wihh + (long)(l * 2 + d) * 1024 * 512, 0L, 1024,
                d ? preB : preF, 0L, 1024, 0,
                b_ih + (l * 2 + d) * 1024, b_hh + (l * 2 + d) * 1024, 1.f);
        }
        lstm_k<<<128, 512, 0, stream>>>(preF, preB,
                                        (const uint4*)(wt_u2 + (long)l * 2 * 65536), xout);
    }

    // emissions = x2_h @ proj_w_h^T + proj_b  (N=66 guarded, fp32 out)
    hgemm_k<<<dim3(128, 1, 1), 256, 0, stream>>>(
        x1h, 512, 0L, 0, projwh, 0L, NG,
        emit, 0L, NG, 0, proj_b, nullptr, 1.f);
    // CRF NLL (blocks 0..63) + Viterbi (blocks 64..127)
    crf_k<<<128, 128, 0, stream>>>(emit, trans, batch_label, out);
}